// Round 8
// baseline (902.041 us; speedup 1.0000x reference)
//
#include <hip/hip_runtime.h>
#include <hip/hip_bf16.h>

// Problem constants (B,T,D,H,KV,HD,RD from reference)
static constexpr int B_  = 2;
static constexpr int T_  = 2048;
static constexpr int D_  = 2048;
static constexpr int H_  = 16;
static constexpr int KV_ = 4;
static constexpr int HD_ = 128;
static constexpr int RD_ = 64;
static constexpr int BT_ = B_ * T_;           // 4096
static constexpr float SCALE_ = 0.08838834764831845f; // 1/sqrt(128)

typedef __attribute__((ext_vector_type(8))) short bf16x8;
typedef __attribute__((ext_vector_type(8))) unsigned short u16x8;
typedef __attribute__((ext_vector_type(4))) float f32x4;

// f32 -> bf16 (RNE) raw bits
__device__ __forceinline__ unsigned short f2bu(float f) {
  unsigned x = __float_as_uint(f);
  unsigned r = (x + 0x7fffu + ((x >> 16) & 1u)) >> 16;
  return (unsigned short)r;
}

// ---------------- f32 -> bf16 elementwise (n divisible by 1024) ----------------
__global__ __launch_bounds__(256) void cvt_bf16(const float* __restrict__ in,
                                                unsigned short* __restrict__ out) {
  const size_t i = ((size_t)blockIdx.x * 256 + threadIdx.x) * 4;
  const float4 f = *(const float4*)(in + i);
  ushort4 o;
  o.x = f2bu(f.x); o.y = f2bu(f.y); o.z = f2bu(f.z); o.w = f2bu(f.w);
  *(ushort4*)(out + i) = o;
}

// ---------------- transpose + convert: in f32 [R,C] -> out bf16 [C,R] ----------------
__global__ __launch_bounds__(256) void t32(const float* __restrict__ in,
                                           unsigned short* __restrict__ out,
                                           int R, int C) {
  __shared__ unsigned short tile[32][36];
  const int r0 = blockIdx.x * 32;
  const int c0 = blockIdx.y * 32;
  const int tid = threadIdx.x;
  {
    const int r = tid >> 3;
    const int c = (tid & 7) * 4;
    const float4 f = *(const float4*)(in + (size_t)(r0 + r) * C + c0 + c);
    ushort4 w;
    w.x = f2bu(f.x); w.y = f2bu(f.y); w.z = f2bu(f.z); w.w = f2bu(f.w);
    *(ushort4*)&tile[r][c] = w;
  }
  __syncthreads();
  {
    const int c = tid >> 3;          // out row (= in col)
    const int r = (tid & 7) * 4;     // out col group (= in rows)
    ushort4 o;
    o.x = tile[r + 0][c];
    o.y = tile[r + 1][c];
    o.z = tile[r + 2][c];
    o.w = tile[r + 3][c];
    *(ushort4*)(out + (size_t)(c0 + c) * R + r0 + r) = o;
  }
}

// ---------------- bf16 MFMA GEMM: C[M,N] = A[M,K] @ Bt[N,K]^T ----------------
// 128x128 tile, BK=32, 256 threads = 4 waves, each wave 64x64 via 4x4 16x16x32 MFMAs.
template <int REMAP>
__global__ __launch_bounds__(256) void gemm_bf16(const unsigned short* __restrict__ A,
                                                 const unsigned short* __restrict__ Bt,
                                                 float* __restrict__ C,
                                                 int M, int N, int K) {
  __shared__ unsigned short As[128][40];
  __shared__ unsigned short Bs[128][40];
  const int tid = threadIdx.x;
  const int lane = tid & 63;
  const int wave = tid >> 6;
  const int n16 = lane & 15;
  const int quad = lane >> 4;
  const int bm = blockIdx.y * 128;
  const int bn = blockIdx.x * 128;
  const int wm = (wave & 1) * 64;
  const int wn = (wave >> 1) * 64;

  const int srow = tid >> 1;         // 0..127
  const int scol = (tid & 1) * 16;   // 0 / 16

  f32x4 acc[4][4];
#pragma unroll
  for (int mi = 0; mi < 4; ++mi)
#pragma unroll
    for (int ni = 0; ni < 4; ++ni) acc[mi][ni] = (f32x4){0.f, 0.f, 0.f, 0.f};

  const unsigned short* ag = A + (size_t)(bm + srow) * K + scol;
  const unsigned short* bg = Bt + (size_t)(bn + srow) * K + scol;

  for (int k0 = 0; k0 < K; k0 += 32) {
    *(u16x8*)&As[srow][scol]     = *(const u16x8*)(ag + k0);
    *(u16x8*)&As[srow][scol + 8] = *(const u16x8*)(ag + k0 + 8);
    *(u16x8*)&Bs[srow][scol]     = *(const u16x8*)(bg + k0);
    *(u16x8*)&Bs[srow][scol + 8] = *(const u16x8*)(bg + k0 + 8);
    __syncthreads();

    bf16x8 af[4], bf[4];
#pragma unroll
    for (int i = 0; i < 4; ++i) {
      af[i] = *(const bf16x8*)&As[wm + i * 16 + n16][quad * 8];
      bf[i] = *(const bf16x8*)&Bs[wn + i * 16 + n16][quad * 8];
    }
#pragma unroll
    for (int mi = 0; mi < 4; ++mi)
#pragma unroll
      for (int ni = 0; ni < 4; ++ni)
        acc[mi][ni] = __builtin_amdgcn_mfma_f32_16x16x32_bf16(af[mi], bf[ni], acc[mi][ni], 0, 0, 0);
    __syncthreads();
  }

#pragma unroll
  for (int mi = 0; mi < 4; ++mi) {
#pragma unroll
    for (int r = 0; r < 4; ++r) {
      const int row = bm + wm + mi * 16 + quad * 4 + r;
#pragma unroll
      for (int ni = 0; ni < 4; ++ni) {
        const int col = bn + wn + ni * 16 + n16;
        const float v = acc[mi][ni][r];
        if (REMAP == 0) {
          C[(size_t)row * N + col] = v;
        } else {
          const int b = row >> 11, t = row & (T_ - 1);
          const int part = col >> 9;
          const int kv = (col >> 7) & 3;
          const int hd = col & 127;
          C[(size_t)part * (B_ * KV_ * T_ * HD_) +
            (((size_t)(b * KV_ + kv) * T_) + t) * HD_ + hd] = v;
        }
      }
    }
  }
}

// ---------------- RoPE Q in place (f32 [BT, H*HD]) ----------------
__global__ __launch_bounds__(256) void rope_q(float* __restrict__ Q,
                                              const float* __restrict__ cosb,
                                              const float* __restrict__ sinb) {
  const int bt = blockIdx.x;
  const int t = bt % T_;
  const int tid = threadIdx.x;
  for (int i = tid; i < H_ * (RD_ / 2); i += 256) {
    const int h = i >> 5;
    const int p = i & 31;
    const float c = cosb[t * 32 + p];
    const float s = sinb[t * 32 + p];
    const size_t base = (size_t)bt * (H_ * HD_) + h * HD_ + 2 * p;
    const float e = Q[base], o = Q[base + 1];
    Q[base]     = e * c - o * s;
    Q[base + 1] = e * s + o * c;
  }
}

// ---------------- RoPE K in place (f32 [B,KV,T,HD]) + bf16 mirror ----------------
__global__ __launch_bounds__(256) void rope_k(float* __restrict__ kout,
                                              const float* __restrict__ cosb,
                                              const float* __restrict__ sinb,
                                              unsigned short* __restrict__ Kbf) {
  const int bt = blockIdx.x;
  const int t = bt % T_;
  const int b = bt / T_;
  const int tid = threadIdx.x;
  for (int i = tid; i < KV_ * (HD_ / 2); i += 256) {
    const int kv = i >> 6;
    const int p = i & 63;
    const size_t idx = (((size_t)(b * KV_ + kv) * T_) + t) * HD_ + 2 * p;
    float e = kout[idx], o = kout[idx + 1];
    if (p < 32) {
      const float c = cosb[t * 32 + p];
      const float s = sinb[t * 32 + p];
      const float re = e * c - o * s;
      const float ro = e * s + o * c;
      e = re; o = ro;
      kout[idx]     = e;
      kout[idx + 1] = o;
    }
    Kbf[idx]     = f2bu(e);
    Kbf[idx + 1] = f2bu(o);
  }
}

// ---------------- V transpose: vout f32 [G,T,HD] -> VbfT bf16 [G,HD,T] ----------------
__global__ __launch_bounds__(256) void v_transpose(const float* __restrict__ vin,
                                                   unsigned short* __restrict__ vt) {
  __shared__ unsigned int tile[32][17];
  const int tid = threadIdx.x;
  const int k0 = blockIdx.x * 32;
  const int d0 = blockIdx.y * 32;
  const int g  = blockIdx.z;
  const float* src = vin + ((size_t)g * T_ + k0) * HD_ + d0;

  {
    const int kr = tid >> 3;
    const int d2 = (tid & 7) * 2;
#pragma unroll
    for (int c = 0; c < 2; ++c) {
      const float2 f = *(const float2*)(src + (size_t)kr * HD_ + (d2 + c) * 2);
      tile[kr][d2 + c] = (unsigned)f2bu(f.x) | ((unsigned)f2bu(f.y) << 16);
    }
  }
  __syncthreads();
  {
    const int dr = tid >> 3;
    const int kc = (tid & 7) * 4;
    const int hi = dr >> 1;
    const int sh = (dr & 1) * 16;
    ushort4 o;
    o.x = (unsigned short)(tile[kc + 0][hi] >> sh);
    o.y = (unsigned short)(tile[kc + 1][hi] >> sh);
    o.z = (unsigned short)(tile[kc + 2][hi] >> sh);
    o.w = (unsigned short)(tile[kc + 3][hi] >> sh);
    *(ushort4*)(vt + ((size_t)g * HD_ + d0 + dr) * T_ + k0 + kc) = o;
  }
}

// ---------------- flash attention: 4 waves/block, one 16-row Q tile per wave ----------------
// No __syncthreads: each wave is fully independent; per-wave LDS regions only
// (wave-lockstep ordering, pinned with __threadfence_block). m/l/alpha in registers
// via shuffle butterflies; S->P layout transpose via per-wave LDS tile.
__global__ __launch_bounds__(256) void attn_flash(const float* __restrict__ Q,
                                                  const unsigned short* __restrict__ Kbf,
                                                  const unsigned short* __restrict__ VbfT,
                                                  unsigned short* __restrict__ O) {
  __shared__ float Sl[4][16][33];
  __shared__ float mA[4][16];

  const int tid = threadIdx.x;
  const int wave = tid >> 6;
  const int lane = tid & 63;
  const int n16 = lane & 15;
  const int quad = lane >> 4;
  const int g = blockIdx.x * 4 + wave;          // 4 consecutive (reversed) qtiles per block
  const int qt = (T_ / 16 - 1) - g;             // heavy tiles first, balanced within block
  const int q0 = qt * 16;
  const int bh = blockIdx.y;
  const int h = bh % H_;
  const int b = bh / H_;
  const int kvh = h >> 2;

  // Q A-frags (scale folded): qf[s] = Q[q0+n16][s*32 + quad*8 + j]
  bf16x8 qf[4];
  {
    const float* qbase = Q + ((size_t)(b * T_ + q0 + n16)) * (H_ * HD_) + h * HD_ + quad * 8;
#pragma unroll
    for (int s = 0; s < 4; ++s) {
      union { bf16x8 v; unsigned short u[8]; } qk;
#pragma unroll
      for (int j = 0; j < 8; ++j) qk.u[j] = f2bu(qbase[s * 32 + j] * SCALE_);
      qf[s] = qk.v;
    }
  }

  float mold[4];                                 // C-layout rows quad*4+r
#pragma unroll
  for (int r = 0; r < 4; ++r) mold[r] = -1e30f;
  float moldA = -1e30f, lrowA = 0.f;             // A-layout row n16

  f32x4 oacc[8];
#pragma unroll
  for (int t = 0; t < 8; ++t) oacc[t] = (f32x4){0.f, 0.f, 0.f, 0.f};

  const unsigned short* ksrc = Kbf + ((size_t)(b * KV_ + kvh)) * T_ * HD_;
  const unsigned short* vtsrc = VbfT + ((size_t)(b * KV_ + kvh)) * HD_ * T_;

  const int kend = q0 + 15;
  for (int kc = 0; kc <= kend; kc += 32) {
    // ---- S = Q K^T (two 16-col tiles), K B-frags direct from global ----
    f32x4 acc0 = (f32x4){0.f, 0.f, 0.f, 0.f};
    f32x4 acc1 = (f32x4){0.f, 0.f, 0.f, 0.f};
    const unsigned short* kr0 = ksrc + (size_t)(kc + n16) * HD_ + quad * 8;
    const unsigned short* kr1 = kr0 + 16 * HD_;
#pragma unroll
    for (int s = 0; s < 4; ++s) {
      acc0 = __builtin_amdgcn_mfma_f32_16x16x32_bf16(qf[s], *(const bf16x8*)(kr0 + s * 32), acc0, 0, 0, 0);
      acc1 = __builtin_amdgcn_mfma_f32_16x16x32_bf16(qf[s], *(const bf16x8*)(kr1 + s * 32), acc1, 0, 0, 0);
    }

    // ---- mask, stash S in per-wave LDS (C-layout), shuffle row-max ----
    f32x4 mnewv;
    float alphaC[4];
#pragma unroll
    for (int r = 0; r < 4; ++r) {
      const int qrow = q0 + quad * 4 + r;
      const float s0 = (kc + n16 <= qrow) ? acc0[r] : -1e30f;
      const float s1 = (kc + 16 + n16 <= qrow) ? acc1[r] : -1e30f;
      Sl[wave][quad * 4 + r][n16] = s0;
      Sl[wave][quad * 4 + r][16 + n16] = s1;
      float mm = fmaxf(s0, s1);
      mm = fmaxf(mm, __shfl_xor(mm, 1));
      mm = fmaxf(mm, __shfl_xor(mm, 2));
      mm = fmaxf(mm, __shfl_xor(mm, 4));
      mm = fmaxf(mm, __shfl_xor(mm, 8));
      const float mn = fmaxf(mold[r], mm);
      mnewv[r] = mn;
      alphaC[r] = __expf(mold[r] - mn);
      mold[r] = mn;
    }
    if (n16 == 0) *(f32x4*)&mA[wave][quad * 4] = mnewv;   // broadcast m to A-layout
    __threadfence_block();

    // ---- P = exp(S - m) in A-layout; shuffle row-sum; l update ----
    const float mAl = mA[wave][n16];
    const float alphaA = __expf(moldA - mAl);
    moldA = mAl;
    float lsum = 0.f;
    union { bf16x8 v; unsigned short u[8]; } pk;
    const float* srow = &Sl[wave][n16][quad * 8];
#pragma unroll
    for (int j = 0; j < 8; ++j) {
      const float p = __expf(srow[j] - mAl);
      lsum += p;
      pk.u[j] = f2bu(p);
    }
    lsum += __shfl_xor(lsum, 16);
    lsum += __shfl_xor(lsum, 32);
    lrowA = alphaA * lrowA + lsum;

    // ---- rescale O, PV with V B-frags direct from global ----
    const int kb = kc + quad * 8;
#pragma unroll
    for (int t = 0; t < 8; ++t) {
      const bf16x8 vf = *(const bf16x8*)(vtsrc + (size_t)(t * 16 + n16) * T_ + kb);
      oacc[t][0] *= alphaC[0]; oacc[t][1] *= alphaC[1];
      oacc[t][2] *= alphaC[2]; oacc[t][3] *= alphaC[3];
      oacc[t] = __builtin_amdgcn_mfma_f32_16x16x32_bf16(pk.v, vf, oacc[t], 0, 0, 0);
    }
  }

  // ---- epilogue: transpose l to C-layout via LDS, normalize, store bf16 ----
  if (quad == 0) mA[wave][n16] = lrowA;
  __threadfence_block();
  const f32x4 lC = *(const f32x4*)&mA[wave][quad * 4];
  unsigned short* obase = O + ((size_t)(b * T_ + q0)) * (H_ * HD_) + h * HD_;
#pragma unroll
  for (int r = 0; r < 4; ++r) {
    const float linv = 1.0f / lC[r];
#pragma unroll
    for (int t = 0; t < 8; ++t) {
      obase[(size_t)(quad * 4 + r) * (H_ * HD_) + t * 16 + n16] = f2bu(oacc[t][r] * linv);
    }
  }
}

extern "C" void kernel_launch(void* const* d_in, const int* in_sizes, int n_in,
                              void* d_out, int out_size, void* d_ws, size_t ws_size,
                              hipStream_t stream) {
  const float* x  = (const float*)d_in[0];
  const float* fc = (const float*)d_in[1];
  const float* fs = (const float*)d_in[2];
  const float* Wq = (const float*)d_in[3];
  const float* Wk = (const float*)d_in[4];
  const float* Wv = (const float*)d_in[5];
  const float* Wo = (const float*)d_in[6];

  // Outputs (f32), concatenated: y | present_k | present_v
  float* yout = (float*)d_out;                          // [B,T,D]
  float* kout = yout + (size_t)B_ * T_ * D_;            // [B,KV,T,HD]
  float* vout = kout + (size_t)B_ * KV_ * T_ * HD_;     // [B,KV,T,HD]
  float* Qb = yout;                                     // f32 Q staging in yout region

  // workspace (bf16, 46.1 MB): xb/Abf (aliased) | Wqt | Wkvt | Wot | Kbf | VbfT
  unsigned short* xb   = (unsigned short*)d_ws;                    // [BT, D]
  unsigned short* Abf  = xb;                                       // alias: xb dead after projections
  unsigned short* Wqt  = xb   + (size_t)BT_ * D_;                  // [2048, 2048]
  unsigned short* Wkvt = Wqt  + (size_t)D_ * D_;                   // [1024, 2048]
  unsigned short* Wot  = Wkvt + (size_t)1024 * D_;                 // [2048, 2048]
  unsigned short* Kbf  = Wot  + (size_t)D_ * D_;                   // [B,KV,T,HD]
  unsigned short* VbfT = Kbf  + (size_t)B_ * KV_ * T_ * HD_;       // [B*KV, HD, T]

  dim3 blk(256);

  // input conversions
  cvt_bf16<<<dim3((BT_ * D_) / 1024), blk, 0, stream>>>(x, xb);
  t32<<<dim3(D_ / 32, D_ / 32), blk, 0, stream>>>(Wq, Wqt, D_, D_);
  t32<<<dim3(D_ / 32, 512 / 32), blk, 0, stream>>>(Wk, Wkvt, D_, 512);
  t32<<<dim3(D_ / 32, 512 / 32), blk, 0, stream>>>(Wv, Wkvt + (size_t)512 * D_, D_, 512);
  t32<<<dim3(D_ / 32, D_ / 32), blk, 0, stream>>>(Wo, Wot, D_, D_);

  // projections (bf16 MFMA, f32 out)
  gemm_bf16<0><<<dim3(D_ / 128, BT_ / 128), blk, 0, stream>>>(xb, Wqt, Qb, BT_, D_, D_);
  gemm_bf16<1><<<dim3(1024 / 128, BT_ / 128), blk, 0, stream>>>(xb, Wkvt, kout, BT_, 1024, D_);

  // RoPE (Q and K in place) + bf16 K mirror; V^T bf16 mirror
  rope_q<<<dim3(BT_), blk, 0, stream>>>(Qb, fc, fs);
  rope_k<<<dim3(BT_), blk, 0, stream>>>(kout, fc, fs, Kbf);
  v_transpose<<<dim3(T_ / 32, HD_ / 32, B_ * KV_), blk, 0, stream>>>(vout, VbfT);

  // flash attention (4 waves/block, barrier-free) -> bf16 Abf
  attn_flash<<<dim3(T_ / 16 / 4, B_ * H_), blk, 0, stream>>>(Qb, Kbf, VbfT, Abf);

  // output projection; overwrites Qb staging with y
  gemm_bf16<0><<<dim3(D_ / 128, BT_ / 128), blk, 0, stream>>>(Abf, Wot, yout, BT_, D_, D_);
}

// Round 9
// 613.219 us; speedup vs baseline: 1.4710x; 1.4710x over previous
//
#include <hip/hip_runtime.h>
#include <hip/hip_bf16.h>

// Problem constants (B,T,D,H,KV,HD,RD from reference)
static constexpr int B_  = 2;
static constexpr int T_  = 2048;
static constexpr int D_  = 2048;
static constexpr int H_  = 16;
static constexpr int KV_ = 4;
static constexpr int HD_ = 128;
static constexpr int RD_ = 64;
static constexpr int BT_ = B_ * T_;           // 4096
static constexpr float SCALE_ = 0.08838834764831845f; // 1/sqrt(128)

typedef __attribute__((ext_vector_type(8))) short bf16x8;
typedef __attribute__((ext_vector_type(8))) unsigned short u16x8;
typedef __attribute__((ext_vector_type(4))) float f32x4;

#define COMPILER_BARRIER() __asm__ __volatile__("" ::: "memory")

// f32 -> bf16 (RNE) raw bits
__device__ __forceinline__ unsigned short f2bu(float f) {
  unsigned x = __float_as_uint(f);
  unsigned r = (x + 0x7fffu + ((x >> 16) & 1u)) >> 16;
  return (unsigned short)r;
}

// ---------------- f32 -> bf16 elementwise (n divisible by 1024) ----------------
__global__ __launch_bounds__(256) void cvt_bf16(const float* __restrict__ in,
                                                unsigned short* __restrict__ out) {
  const size_t i = ((size_t)blockIdx.x * 256 + threadIdx.x) * 4;
  const float4 f = *(const float4*)(in + i);
  ushort4 o;
  o.x = f2bu(f.x); o.y = f2bu(f.y); o.z = f2bu(f.z); o.w = f2bu(f.w);
  *(ushort4*)(out + i) = o;
}

// ---------------- transpose + convert: in f32 [R,C] -> out bf16 [C,R] ----------------
__global__ __launch_bounds__(256) void t32(const float* __restrict__ in,
                                           unsigned short* __restrict__ out,
                                           int R, int C) {
  __shared__ unsigned short tile[32][36];
  const int r0 = blockIdx.x * 32;
  const int c0 = blockIdx.y * 32;
  const int tid = threadIdx.x;
  {
    const int r = tid >> 3;
    const int c = (tid & 7) * 4;
    const float4 f = *(const float4*)(in + (size_t)(r0 + r) * C + c0 + c);
    ushort4 w;
    w.x = f2bu(f.x); w.y = f2bu(f.y); w.z = f2bu(f.z); w.w = f2bu(f.w);
    *(ushort4*)&tile[r][c] = w;
  }
  __syncthreads();
  {
    const int c = tid >> 3;
    const int r = (tid & 7) * 4;
    ushort4 o;
    o.x = tile[r + 0][c];
    o.y = tile[r + 1][c];
    o.z = tile[r + 2][c];
    o.w = tile[r + 3][c];
    *(ushort4*)(out + (size_t)(c0 + c) * R + r0 + r) = o;
  }
}

// ---------------- bf16 MFMA GEMM: C[M,N] = A[M,K] @ Bt[N,K]^T ----------------
template <int REMAP>
__global__ __launch_bounds__(256) void gemm_bf16(const unsigned short* __restrict__ A,
                                                 const unsigned short* __restrict__ Bt,
                                                 float* __restrict__ C,
                                                 int M, int N, int K) {
  __shared__ unsigned short As[128][40];
  __shared__ unsigned short Bs[128][40];
  const int tid = threadIdx.x;
  const int lane = tid & 63;
  const int wave = tid >> 6;
  const int n16 = lane & 15;
  const int quad = lane >> 4;
  const int bm = blockIdx.y * 128;
  const int bn = blockIdx.x * 128;
  const int wm = (wave & 1) * 64;
  const int wn = (wave >> 1) * 64;

  const int srow = tid >> 1;
  const int scol = (tid & 1) * 16;

  f32x4 acc[4][4];
#pragma unroll
  for (int mi = 0; mi < 4; ++mi)
#pragma unroll
    for (int ni = 0; ni < 4; ++ni) acc[mi][ni] = (f32x4){0.f, 0.f, 0.f, 0.f};

  const unsigned short* ag = A + (size_t)(bm + srow) * K + scol;
  const unsigned short* bg = Bt + (size_t)(bn + srow) * K + scol;

  for (int k0 = 0; k0 < K; k0 += 32) {
    *(u16x8*)&As[srow][scol]     = *(const u16x8*)(ag + k0);
    *(u16x8*)&As[srow][scol + 8] = *(const u16x8*)(ag + k0 + 8);
    *(u16x8*)&Bs[srow][scol]     = *(const u16x8*)(bg + k0);
    *(u16x8*)&Bs[srow][scol + 8] = *(const u16x8*)(bg + k0 + 8);
    __syncthreads();

    bf16x8 af[4], bf[4];
#pragma unroll
    for (int i = 0; i < 4; ++i) {
      af[i] = *(const bf16x8*)&As[wm + i * 16 + n16][quad * 8];
      bf[i] = *(const bf16x8*)&Bs[wn + i * 16 + n16][quad * 8];
    }
#pragma unroll
    for (int mi = 0; mi < 4; ++mi)
#pragma unroll
      for (int ni = 0; ni < 4; ++ni)
        acc[mi][ni] = __builtin_amdgcn_mfma_f32_16x16x32_bf16(af[mi], bf[ni], acc[mi][ni], 0, 0, 0);
    __syncthreads();
  }

#pragma unroll
  for (int mi = 0; mi < 4; ++mi) {
#pragma unroll
    for (int r = 0; r < 4; ++r) {
      const int row = bm + wm + mi * 16 + quad * 4 + r;
#pragma unroll
      for (int ni = 0; ni < 4; ++ni) {
        const int col = bn + wn + ni * 16 + n16;
        const float v = acc[mi][ni][r];
        if (REMAP == 0) {
          C[(size_t)row * N + col] = v;
        } else {
          const int b = row >> 11, t = row & (T_ - 1);
          const int part = col >> 9;
          const int kv = (col >> 7) & 3;
          const int hd = col & 127;
          C[(size_t)part * (B_ * KV_ * T_ * HD_) +
            (((size_t)(b * KV_ + kv) * T_) + t) * HD_ + hd] = v;
        }
      }
    }
  }
}

// ---------------- RoPE Q in place (f32 [BT, H*HD]) ----------------
__global__ __launch_bounds__(256) void rope_q(float* __restrict__ Q,
                                              const float* __restrict__ cosb,
                                              const float* __restrict__ sinb) {
  const int bt = blockIdx.x;
  const int t = bt % T_;
  const int tid = threadIdx.x;
  for (int i = tid; i < H_ * (RD_ / 2); i += 256) {
    const int h = i >> 5;
    const int p = i & 31;
    const float c = cosb[t * 32 + p];
    const float s = sinb[t * 32 + p];
    const size_t base = (size_t)bt * (H_ * HD_) + h * HD_ + 2 * p;
    const float e = Q[base], o = Q[base + 1];
    Q[base]     = e * c - o * s;
    Q[base + 1] = e * s + o * c;
  }
}

// ---------------- RoPE K in place (f32 [B,KV,T,HD]) + bf16 mirror ----------------
__global__ __launch_bounds__(256) void rope_k(float* __restrict__ kout,
                                              const float* __restrict__ cosb,
                                              const float* __restrict__ sinb,
                                              unsigned short* __restrict__ Kbf) {
  const int bt = blockIdx.x;
  const int t = bt % T_;
  const int b = bt / T_;
  const int tid = threadIdx.x;
  for (int i = tid; i < KV_ * (HD_ / 2); i += 256) {
    const int kv = i >> 6;
    const int p = i & 63;
    const size_t idx = (((size_t)(b * KV_ + kv) * T_) + t) * HD_ + 2 * p;
    float e = kout[idx], o = kout[idx + 1];
    if (p < 32) {
      const float c = cosb[t * 32 + p];
      const float s = sinb[t * 32 + p];
      const float re = e * c - o * s;
      const float ro = e * s + o * c;
      e = re; o = ro;
      kout[idx]     = e;
      kout[idx + 1] = o;
    }
    Kbf[idx]     = f2bu(e);
    Kbf[idx + 1] = f2bu(o);
  }
}

// ---------------- V transpose: vout f32 [G,T,HD] -> VbfT bf16 [G,HD,T] ----------------
__global__ __launch_bounds__(256) void v_transpose(const float* __restrict__ vin,
                                                   unsigned short* __restrict__ vt) {
  __shared__ unsigned int tile[32][17];
  const int tid = threadIdx.x;
  const int k0 = blockIdx.x * 32;
  const int d0 = blockIdx.y * 32;
  const int g  = blockIdx.z;
  const float* src = vin + ((size_t)g * T_ + k0) * HD_ + d0;

  {
    const int kr = tid >> 3;
    const int d2 = (tid & 7) * 2;
#pragma unroll
    for (int c = 0; c < 2; ++c) {
      const float2 f = *(const float2*)(src + (size_t)kr * HD_ + (d2 + c) * 2);
      tile[kr][d2 + c] = (unsigned)f2bu(f.x) | ((unsigned)f2bu(f.y) << 16);
    }
  }
  __syncthreads();
  {
    const int dr = tid >> 3;
    const int kc = (tid & 7) * 4;
    const int hi = dr >> 1;
    const int sh = (dr & 1) * 16;
    ushort4 o;
    o.x = (unsigned short)(tile[kc + 0][hi] >> sh);
    o.y = (unsigned short)(tile[kc + 1][hi] >> sh);
    o.z = (unsigned short)(tile[kc + 2][hi] >> sh);
    o.w = (unsigned short)(tile[kc + 3][hi] >> sh);
    *(ushort4*)(vt + ((size_t)g * HD_ + d0 + dr) * T_ + k0 + kc) = o;
  }
}

// ---------------- flash attention: 1 wave/block, 32-row Q tile (2 row-groups) ----------------
// K/V fragment loads shared across both row-groups (halves L2 traffic, 2 indep chains).
// Same-wave LDS transposes ordered by the in-order DS pipe + compiler barriers only.
__global__ __launch_bounds__(64) void attn_flash(const float* __restrict__ Q,
                                                 const unsigned short* __restrict__ Kbf,
                                                 const unsigned short* __restrict__ VbfT,
                                                 unsigned short* __restrict__ O) {
  __shared__ float Sl[32][33];
  __shared__ float mA[32];

  const int lane = threadIdx.x;
  const int n16 = lane & 15;
  const int quad = lane >> 4;
  const int qt = (T_ / 32 - 1) - blockIdx.x;    // heavy tiles dispatched first
  const int q0 = qt * 32;
  const int bh = blockIdx.y;
  const int h = bh % H_;
  const int b = bh / H_;
  const int kvh = h >> 2;

  // Q A-frags for both 16-row groups (scale folded in)
  bf16x8 qf[2][4];
#pragma unroll
  for (int G = 0; G < 2; ++G) {
    const float* qbase = Q + ((size_t)(b * T_ + q0 + G * 16 + n16)) * (H_ * HD_) + h * HD_ + quad * 8;
#pragma unroll
    for (int s = 0; s < 4; ++s) {
      union { bf16x8 v; unsigned short u[8]; } qk;
#pragma unroll
      for (int j = 0; j < 8; ++j) qk.u[j] = f2bu(qbase[s * 32 + j] * SCALE_);
      qf[G][s] = qk.v;
    }
  }

  float mold[2][4];
#pragma unroll
  for (int G = 0; G < 2; ++G)
#pragma unroll
    for (int r = 0; r < 4; ++r) mold[G][r] = -1e30f;
  float moldA[2] = {-1e30f, -1e30f};
  float lrow[2] = {0.f, 0.f};

  f32x4 oacc[2][8];
#pragma unroll
  for (int G = 0; G < 2; ++G)
#pragma unroll
    for (int t = 0; t < 8; ++t) oacc[G][t] = (f32x4){0.f, 0.f, 0.f, 0.f};

  const unsigned short* ksrc = Kbf + ((size_t)(b * KV_ + kvh)) * T_ * HD_;
  const unsigned short* vtsrc = VbfT + ((size_t)(b * KV_ + kvh)) * HD_ * T_;

  const int kend = q0 + 31;
  for (int kc = 0; kc <= kend; kc += 32) {
    // ---- shared K frags, QK^T for both row-groups ----
    const unsigned short* kr0 = ksrc + (size_t)(kc + n16) * HD_ + quad * 8;
    const unsigned short* kr1 = kr0 + 16 * HD_;
    f32x4 acc[2][2];
    acc[0][0] = acc[0][1] = acc[1][0] = acc[1][1] = (f32x4){0.f, 0.f, 0.f, 0.f};
#pragma unroll
    for (int s = 0; s < 4; ++s) {
      const bf16x8 kf0 = *(const bf16x8*)(kr0 + s * 32);
      const bf16x8 kf1 = *(const bf16x8*)(kr1 + s * 32);
      acc[0][0] = __builtin_amdgcn_mfma_f32_16x16x32_bf16(qf[0][s], kf0, acc[0][0], 0, 0, 0);
      acc[0][1] = __builtin_amdgcn_mfma_f32_16x16x32_bf16(qf[0][s], kf1, acc[0][1], 0, 0, 0);
      acc[1][0] = __builtin_amdgcn_mfma_f32_16x16x32_bf16(qf[1][s], kf0, acc[1][0], 0, 0, 0);
      acc[1][1] = __builtin_amdgcn_mfma_f32_16x16x32_bf16(qf[1][s], kf1, acc[1][1], 0, 0, 0);
    }

    // ---- mask, stash S (C-layout), shuffle row-max, m/alpha update ----
    float alphaC[2][4];
#pragma unroll
    for (int G = 0; G < 2; ++G) {
      f32x4 mnewv;
#pragma unroll
      for (int r = 0; r < 4; ++r) {
        const int qrow = q0 + G * 16 + quad * 4 + r;
        const float s0 = (kc + n16 <= qrow) ? acc[G][0][r] : -1e30f;
        const float s1 = (kc + 16 + n16 <= qrow) ? acc[G][1][r] : -1e30f;
        Sl[G * 16 + quad * 4 + r][n16] = s0;
        Sl[G * 16 + quad * 4 + r][16 + n16] = s1;
        float mm = fmaxf(s0, s1);
        mm = fmaxf(mm, __shfl_xor(mm, 1));
        mm = fmaxf(mm, __shfl_xor(mm, 2));
        mm = fmaxf(mm, __shfl_xor(mm, 4));
        mm = fmaxf(mm, __shfl_xor(mm, 8));
        const float mn = fmaxf(mold[G][r], mm);
        mnewv[r] = mn;
        alphaC[G][r] = __expf(mold[G][r] - mn);
        mold[G][r] = mn;
      }
      if (n16 == 0) *(f32x4*)&mA[G * 16 + quad * 4] = mnewv;
    }
    COMPILER_BARRIER();

    // ---- P = exp(S - m) in A-layout; shuffle row-sum; l update ----
    union { bf16x8 v; unsigned short u[8]; } pk[2];
#pragma unroll
    for (int G = 0; G < 2; ++G) {
      const float mAl = mA[G * 16 + n16];
      const float alphaA = __expf(moldA[G] - mAl);
      moldA[G] = mAl;
      float lsum = 0.f;
      const float* srow = &Sl[G * 16 + n16][quad * 8];
#pragma unroll
      for (int j = 0; j < 8; ++j) {
        const float p = __expf(srow[j] - mAl);
        lsum += p;
        pk[G].u[j] = f2bu(p);
      }
      lsum += __shfl_xor(lsum, 16);
      lsum += __shfl_xor(lsum, 32);
      lrow[G] = alphaA * lrow[G] + lsum;
    }

    // ---- rescale O, PV: shared V frags serve both row-groups ----
    const int kb = kc + quad * 8;
#pragma unroll
    for (int t = 0; t < 8; ++t) {
      const bf16x8 vf = *(const bf16x8*)(vtsrc + (size_t)(t * 16 + n16) * T_ + kb);
#pragma unroll
      for (int G = 0; G < 2; ++G) {
        oacc[G][t][0] *= alphaC[G][0]; oacc[G][t][1] *= alphaC[G][1];
        oacc[G][t][2] *= alphaC[G][2]; oacc[G][t][3] *= alphaC[G][3];
        oacc[G][t] = __builtin_amdgcn_mfma_f32_16x16x32_bf16(pk[G].v, vf, oacc[G][t], 0, 0, 0);
      }
    }
    COMPILER_BARRIER();   // next iteration's Sl writes must not pass this chunk's reads
  }

  // ---- epilogue: l -> C-layout via LDS, normalize, store bf16 ----
  if (quad == 0) { mA[n16] = lrow[0]; mA[16 + n16] = lrow[1]; }
  COMPILER_BARRIER();
#pragma unroll
  for (int G = 0; G < 2; ++G) {
    const f32x4 lC = *(const f32x4*)&mA[G * 16 + quad * 4];
    unsigned short* obase = O + ((size_t)(b * T_ + q0 + G * 16)) * (H_ * HD_) + h * HD_;
#pragma unroll
    for (int r = 0; r < 4; ++r) {
      const float linv = 1.0f / lC[r];
#pragma unroll
      for (int t = 0; t < 8; ++t) {
        obase[(size_t)(quad * 4 + r) * (H_ * HD_) + t * 16 + n16] = f2bu(oacc[G][t][r] * linv);
      }
    }
  }
}

extern "C" void kernel_launch(void* const* d_in, const int* in_sizes, int n_in,
                              void* d_out, int out_size, void* d_ws, size_t ws_size,
                              hipStream_t stream) {
  const float* x  = (const float*)d_in[0];
  const float* fc = (const float*)d_in[1];
  const float* fs = (const float*)d_in[2];
  const float* Wq = (const float*)d_in[3];
  const float* Wk = (const float*)d_in[4];
  const float* Wv = (const float*)d_in[5];
  const float* Wo = (const float*)d_in[6];

  // Outputs (f32), concatenated: y | present_k | present_v
  float* yout = (float*)d_out;                          // [B,T,D]
  float* kout = yout + (size_t)B_ * T_ * D_;            // [B,KV,T,HD]
  float* vout = kout + (size_t)B_ * KV_ * T_ * HD_;     // [B,KV,T,HD]
  float* Qb = yout;                                     // f32 Q staging in yout region

  // workspace (bf16, 46.1 MB): xb/Abf (aliased) | Wqt | Wkvt | Wot | Kbf | VbfT
  unsigned short* xb   = (unsigned short*)d_ws;                    // [BT, D]
  unsigned short* Abf  = xb;                                       // alias: xb dead after projections
  unsigned short* Wqt  = xb   + (size_t)BT_ * D_;                  // [2048, 2048]
  unsigned short* Wkvt = Wqt  + (size_t)D_ * D_;                   // [1024, 2048]
  unsigned short* Wot  = Wkvt + (size_t)1024 * D_;                 // [2048, 2048]
  unsigned short* Kbf  = Wot  + (size_t)D_ * D_;                   // [B,KV,T,HD]
  unsigned short* VbfT = Kbf  + (size_t)B_ * KV_ * T_ * HD_;       // [B*KV, HD, T]

  dim3 blk(256);

  // input conversions
  cvt_bf16<<<dim3((BT_ * D_) / 1024), blk, 0, stream>>>(x, xb);
  t32<<<dim3(D_ / 32, D_ / 32), blk, 0, stream>>>(Wq, Wqt, D_, D_);
  t32<<<dim3(D_ / 32, 512 / 32), blk, 0, stream>>>(Wk, Wkvt, D_, 512);
  t32<<<dim3(D_ / 32, 512 / 32), blk, 0, stream>>>(Wv, Wkvt + (size_t)512 * D_, D_, 512);
  t32<<<dim3(D_ / 32, D_ / 32), blk, 0, stream>>>(Wo, Wot, D_, D_);

  // projections (bf16 MFMA, f32 out)
  gemm_bf16<0><<<dim3(D_ / 128, BT_ / 128), blk, 0, stream>>>(xb, Wqt, Qb, BT_, D_, D_);
  gemm_bf16<1><<<dim3(1024 / 128, BT_ / 128), blk, 0, stream>>>(xb, Wkvt, kout, BT_, 1024, D_);

  // RoPE (Q and K in place) + bf16 K mirror; V^T bf16 mirror
  rope_q<<<dim3(BT_), blk, 0, stream>>>(Qb, fc, fs);
  rope_k<<<dim3(BT_), blk, 0, stream>>>(kout, fc, fs, Kbf);
  v_transpose<<<dim3(T_ / 32, HD_ / 32, B_ * KV_), blk, 0, stream>>>(vout, VbfT);

  // flash attention (1 wave/block, 32-row Q tile) -> bf16 Abf
  attn_flash<<<dim3(T_ / 32, B_ * H_), dim3(64), 0, stream>>>(Qb, Kbf, VbfT, Abf);

  // output projection; overwrites Qb staging with y
  gemm_bf16<0><<<dim3(D_ / 128, BT_ / 128), blk, 0, stream>>>(Abf, Wot, yout, BT_, D_, D_);
}